// Round 5
// baseline (449.667 us; speedup 1.0000x reference)
//
#include <hip/hip_runtime.h>
#include <hip/hip_bf16.h>

// ExpertChoiceRouter: scores = sigmoid(x @ w); top-k (k = int(N*0.67)) mask; aux = -mean(top)*1e-3
// x: [N=16384, D=2048] f32; mask all-True (ignored); w: [1, D] f32
// d_out: N mask floats (0.0/1.0) + 1 aux float.
//
// FUSED single kernel: 1024 blocks x 1024 threads score 16 tokens each
// (wave-per-token). Each block releases its scores with __threadfence() and
// takes a ticket (device-scope atomicAdd, cross-XCD safe); the LAST block
// acquires and runs the radix top-k select inline. No spin, no co-residency
// assumption -> safe under undefined dispatch order (G16).

#define D_MODEL 2048
#define NSEL_THREADS 1024
#define CHUNK 16            // n / NSEL_THREADS

__global__ __launch_bounds__(NSEL_THREADS) void router_fused_kernel(
        const float* __restrict__ x,
        const float* __restrict__ w,
        float* __restrict__ scores,
        unsigned int* __restrict__ ticket_ctr,
        float* __restrict__ out,
        int n, int k) {
    __shared__ unsigned int whist[16 * 257];       // per-wave histograms, padded
    __shared__ int wsum[16];
    __shared__ unsigned int sel_prefix_sh;
    __shared__ int sel_remaining_sh;
    __shared__ int warp_part[16];
    __shared__ double sum_sh[16];
    __shared__ unsigned int ticket_sh;

    const int tid = threadIdx.x;
    const int wv  = tid >> 6;
    const int ln  = tid & 63;

    // ================= phase 1: score 16 tokens (wave-per-token) ===========
    {
        const int tok = blockIdx.x * 16 + wv;      // gridDim=1024, 16 waves/blk
        const float4* xr = (const float4*)(x + (size_t)tok * D_MODEL);
        const float4* wr = (const float4*)w;

        double acc = 0.0;
#pragma unroll
        for (int i = 0; i < D_MODEL / 256; ++i) {  // 8 iters, 1KiB/wave each
            float4 xv = xr[i * 64 + ln];
            float4 wv4 = wr[i * 64 + ln];
            acc += (double)xv.x * (double)wv4.x + (double)xv.y * (double)wv4.y
                 + (double)xv.z * (double)wv4.z + (double)xv.w * (double)wv4.w;
        }
        for (int off = 32; off > 0; off >>= 1)
            acc += __shfl_down(acc, off, 64);
        if (ln == 0) {
            float logit = (float)acc;
            scores[tok] = 1.0f / (1.0f + expf(-logit));
        }
    }

    // ================= ticket: last block proceeds to select ================
    __syncthreads();                                // all waves' stores issued
    __threadfence();                                // device-scope release
    if (tid == 0) ticket_sh = atomicAdd(ticket_ctr, 1u);
    __syncthreads();
    if (ticket_sh != (unsigned int)(gridDim.x - 1)) return;
    __threadfence();                                // device-scope acquire

    // ================= phase 2: radix top-k select (last block only) ========
    const int beg = tid * CHUNK;

    unsigned int key[CHUNK];
    {
        const uint4* sv = (const uint4*)(scores + beg);
#pragma unroll
        for (int q = 0; q < CHUNK / 4; ++q) {
            uint4 v = sv[q];
            key[q * 4 + 0] = v.x; key[q * 4 + 1] = v.y;
            key[q * 4 + 2] = v.z; key[q * 4 + 3] = v.w;
        }
    }

    unsigned int prefix = 0;
    unsigned int pmask  = 0;
    int remaining = k;

#pragma unroll
    for (int pass = 0; pass < 4; ++pass) {
        const int shift = 24 - pass * 8;
        for (int i = tid; i < 16 * 257; i += NSEL_THREADS) whist[i] = 0;
        __syncthreads();

        if (pass == 0) {
            // sign+exp byte is concentrated (~2 values for sigmoid outputs):
            // leader-ballot aggregation avoids same-address atomic serialization
#pragma unroll
            for (int j = 0; j < CHUNK; ++j) {
                unsigned int dig = key[j] >> 24;
                unsigned long long pending = ~0ull;
                while (pending) {
                    int lead = __ffsll((unsigned long long)pending) - 1;
                    unsigned int d0 = __shfl((int)dig, lead, 64);
                    unsigned long long match = __ballot(dig == d0) & pending;
                    if (ln == lead)
                        atomicAdd(&whist[wv * 257 + d0], (unsigned int)__popcll(match));
                    pending &= ~match;
                }
            }
        } else {
#pragma unroll
            for (int j = 0; j < CHUNK; ++j)
                if ((key[j] & pmask) == prefix)
                    atomicAdd(&whist[wv * 257 + ((key[j] >> shift) & 255u)], 1u);
        }
        __syncthreads();

        // threads 0..255: bin totals + parallel suffix scan (bins descending)
        int c = 0;
        if (tid < 256) {
#pragma unroll
            for (int w2 = 0; w2 < 16; ++w2) c += (int)whist[w2 * 257 + tid];
        }
        int sc = c;
        for (int off = 1; off < 64; off <<= 1) {
            int v = __shfl_down(sc, off, 64);
            if (ln + off < 64) sc += v;
        }
        if (tid < 256 && ln == 0) wsum[wv] = sc;
        __syncthreads();
        if (tid < 256) {
            int hi = 0;
            for (int w2 = wv + 1; w2 < 4; ++w2) hi += wsum[w2];
            const int S_excl = hi + (sc - c);
            if (S_excl < remaining && remaining <= S_excl + c) {
                sel_prefix_sh    = prefix | ((unsigned int)tid << shift);
                sel_remaining_sh = remaining - S_excl;
            }
        }
        __syncthreads();
        prefix    = sel_prefix_sh;
        remaining = sel_remaining_sh;
        pmask    |= (0xFFu << shift);
        __syncthreads();
    }
    const unsigned int tkey = prefix;
    const int ties_needed   = remaining;

    // ---- sum of strictly-greater scores ----
    double lsum = 0.0;
#pragma unroll
    for (int j = 0; j < CHUNK; ++j)
        if (key[j] > tkey) lsum += (double)__uint_as_float(key[j]);
    for (int off = 32; off > 0; off >>= 1)
        lsum += __shfl_down(lsum, off, 64);
    if (ln == 0) sum_sh[wv] = lsum;

    // ---- tie ranking: exclusive prefix over per-thread tie counts ----
    int lties = 0;
#pragma unroll
    for (int j = 0; j < CHUNK; ++j)
        if (key[j] == tkey) ++lties;

    int sc2 = lties;
    for (int off = 1; off < 64; off <<= 1) {
        int v = __shfl_up(sc2, off, 64);
        if (ln >= off) sc2 += v;
    }
    if (ln == 63) warp_part[wv] = sc2;
    __syncthreads();
    if (wv == 0 && ln < 16) {
        int v = warp_part[ln];
        for (int off = 1; off < 16; off <<= 1) {
            int u = __shfl_up(v, off, 64);
            if (ln >= off) v += u;
        }
        warp_part[ln] = v;
    }
    __syncthreads();
    const int wave_off = (wv == 0) ? 0 : warp_part[wv - 1];
    const int excl = wave_off + sc2 - lties;

    // ---- write mask, vectorized ----
    float mv[CHUNK];
    int taken = 0;
#pragma unroll
    for (int j = 0; j < CHUNK; ++j) {
        if (key[j] > tkey) {
            mv[j] = 1.0f;
        } else if (key[j] == tkey) {
            mv[j] = (excl + taken < ties_needed) ? 1.0f : 0.0f;
            ++taken;
        } else {
            mv[j] = 0.0f;
        }
    }
    {
        float4* ov = (float4*)(out + beg);
#pragma unroll
        for (int q = 0; q < CHUNK / 4; ++q)
            ov[q] = make_float4(mv[q * 4 + 0], mv[q * 4 + 1],
                                mv[q * 4 + 2], mv[q * 4 + 3]);
    }

    // ---- aux loss ----
    if (tid == 0) {
        double s = 0.0;
        for (int i = 0; i < 16; ++i) s += sum_sh[i];
        s += (double)ties_needed * (double)__uint_as_float(tkey);
        out[n] = (float)(-(s / (double)k) * 0.001);
    }
}

extern "C" void kernel_launch(void* const* d_in, const int* in_sizes, int n_in,
                              void* d_out, int out_size, void* d_ws, size_t ws_size,
                              hipStream_t stream) {
    const float* x = (const float*)d_in[0];
    // d_in[1] = current_mask, all-True by construction -> no-op in the math
    const float* w = (const float*)d_in[2];

    const int d = in_sizes[2];             // 2048
    const int n = in_sizes[0] / d;         // 16384

    float* scores = (float*)d_ws;                          // n floats
    unsigned int* ticket = (unsigned int*)((char*)d_ws + (size_t)n * 4);
    float* out = (float*)d_out;

    int k = (int)((double)n * 0.67);
    if (k < 1) k = 1;

    (void)hipMemsetAsync(ticket, 0, 4, stream);  // d_ws is poisoned 0xAA each call
    router_fused_kernel<<<n / 16, NSEL_THREADS, 0, stream>>>(
        x, w, scores, ticket, out, n, k);
}

// Round 6
// 212.079 us; speedup vs baseline: 2.1203x; 2.1203x over previous
//
#include <hip/hip_runtime.h>
#include <hip/hip_bf16.h>

// ExpertChoiceRouter: scores = sigmoid(x @ w); top-k (k = int(N*0.67)) mask; aux = -mean(top)*1e-3
// x: [N=16384, D=2048] f32; mask all-True (ignored); w: [1, D] f32
// d_out: N mask floats (0.0/1.0) + 1 aux float.
//
// FUSED, fence-light design (R5 post-mortem: per-thread __threadfence() = L2
// wb+inv per wave = 280 us of TCC serialization):
//  * scores are written with AGENT-scope relaxed atomic stores -> bypass the
//    non-coherent per-XCD L2, land at the coherent point (L3). No flush needed.
//  * __syncthreads() drains each wave's vmcnt(0) before tid0 takes a relaxed
//    device-scope ticket -> when the last ticket is observed, all scores are
//    physically in L3.
//  * ONLY the last block executes one __threadfence() (single L2 inv on one
//    XCD) so its plain vectorized uint4 loads refetch L3 truth.

#define D_MODEL 2048
#define NSEL_THREADS 1024
#define CHUNK 16            // n / NSEL_THREADS

__global__ __launch_bounds__(NSEL_THREADS) void router_fused_kernel(
        const float* __restrict__ x,
        const float* __restrict__ w,
        float* __restrict__ scores,
        unsigned int* __restrict__ ticket_ctr,
        float* __restrict__ out,
        int n, int k) {
    __shared__ unsigned int whist[16 * 257];       // per-wave histograms, padded
    __shared__ int wsum[16];
    __shared__ unsigned int sel_prefix_sh;
    __shared__ int sel_remaining_sh;
    __shared__ int warp_part[16];
    __shared__ double sum_sh[16];
    __shared__ unsigned int ticket_sh;

    const int tid = threadIdx.x;
    const int wv  = tid >> 6;
    const int ln  = tid & 63;

    // ================= phase 1: score 16 tokens (wave-per-token) ===========
    {
        const int tok = blockIdx.x * 16 + wv;      // gridDim=1024, 16 waves/blk
        const float4* xr = (const float4*)(x + (size_t)tok * D_MODEL);
        const float4* wr = (const float4*)w;

        double acc = 0.0;
#pragma unroll
        for (int i = 0; i < D_MODEL / 256; ++i) {  // 8 iters, 1KiB/wave each
            float4 xv = xr[i * 64 + ln];
            float4 wv4 = wr[i * 64 + ln];
            acc += (double)xv.x * (double)wv4.x + (double)xv.y * (double)wv4.y
                 + (double)xv.z * (double)wv4.z + (double)xv.w * (double)wv4.w;
        }
        for (int off = 32; off > 0; off >>= 1)
            acc += __shfl_down(acc, off, 64);
        if (ln == 0) {
            float logit = (float)acc;
            float sval = 1.0f / (1.0f + expf(-logit));
            // agent-scope store: bypasses non-coherent L2, lands at L3
            __hip_atomic_store(&scores[tok], sval, __ATOMIC_RELAXED,
                               __HIP_MEMORY_SCOPE_AGENT);
        }
    }

    // ================= ticket: last block proceeds to select ================
    __syncthreads();   // drains every wave's vmcnt(0) -> scores are at L3
    if (tid == 0) ticket_sh = atomicAdd(ticket_ctr, 1u);  // relaxed, device-scope
    __syncthreads();
    if (ticket_sh != (unsigned int)(gridDim.x - 1)) return;
    __threadfence();   // last block only: one L2 inv so plain loads see L3 truth

    // ================= phase 2: radix top-k select (last block only) ========
    const int beg = tid * CHUNK;

    unsigned int key[CHUNK];
    {
        const uint4* sv = (const uint4*)(scores + beg);
#pragma unroll
        for (int q = 0; q < CHUNK / 4; ++q) {
            uint4 v = sv[q];
            key[q * 4 + 0] = v.x; key[q * 4 + 1] = v.y;
            key[q * 4 + 2] = v.z; key[q * 4 + 3] = v.w;
        }
    }

    unsigned int prefix = 0;
    unsigned int pmask  = 0;
    int remaining = k;

#pragma unroll
    for (int pass = 0; pass < 4; ++pass) {
        const int shift = 24 - pass * 8;
        for (int i = tid; i < 16 * 257; i += NSEL_THREADS) whist[i] = 0;
        __syncthreads();

        if (pass == 0) {
            // sign+exp byte is concentrated (~2 values for sigmoid outputs):
            // leader-ballot aggregation avoids same-address atomic serialization
#pragma unroll
            for (int j = 0; j < CHUNK; ++j) {
                unsigned int dig = key[j] >> 24;
                unsigned long long pending = ~0ull;
                while (pending) {
                    int lead = __ffsll((unsigned long long)pending) - 1;
                    unsigned int d0 = __shfl((int)dig, lead, 64);
                    unsigned long long match = __ballot(dig == d0) & pending;
                    if (ln == lead)
                        atomicAdd(&whist[wv * 257 + d0], (unsigned int)__popcll(match));
                    pending &= ~match;
                }
            }
        } else {
#pragma unroll
            for (int j = 0; j < CHUNK; ++j)
                if ((key[j] & pmask) == prefix)
                    atomicAdd(&whist[wv * 257 + ((key[j] >> shift) & 255u)], 1u);
        }
        __syncthreads();

        // threads 0..255: bin totals + parallel suffix scan (bins descending)
        int c = 0;
        if (tid < 256) {
#pragma unroll
            for (int w2 = 0; w2 < 16; ++w2) c += (int)whist[w2 * 257 + tid];
        }
        int sc = c;
        for (int off = 1; off < 64; off <<= 1) {
            int v = __shfl_down(sc, off, 64);
            if (ln + off < 64) sc += v;
        }
        if (tid < 256 && ln == 0) wsum[wv] = sc;
        __syncthreads();
        if (tid < 256) {
            int hi = 0;
            for (int w2 = wv + 1; w2 < 4; ++w2) hi += wsum[w2];
            const int S_excl = hi + (sc - c);
            if (S_excl < remaining && remaining <= S_excl + c) {
                sel_prefix_sh    = prefix | ((unsigned int)tid << shift);
                sel_remaining_sh = remaining - S_excl;
            }
        }
        __syncthreads();
        prefix    = sel_prefix_sh;
        remaining = sel_remaining_sh;
        pmask    |= (0xFFu << shift);
        __syncthreads();
    }
    const unsigned int tkey = prefix;
    const int ties_needed   = remaining;

    // ---- sum of strictly-greater scores ----
    double lsum = 0.0;
#pragma unroll
    for (int j = 0; j < CHUNK; ++j)
        if (key[j] > tkey) lsum += (double)__uint_as_float(key[j]);
    for (int off = 32; off > 0; off >>= 1)
        lsum += __shfl_down(lsum, off, 64);
    if (ln == 0) sum_sh[wv] = lsum;

    // ---- tie ranking: exclusive prefix over per-thread tie counts ----
    int lties = 0;
#pragma unroll
    for (int j = 0; j < CHUNK; ++j)
        if (key[j] == tkey) ++lties;

    int sc2 = lties;
    for (int off = 1; off < 64; off <<= 1) {
        int v = __shfl_up(sc2, off, 64);
        if (ln >= off) sc2 += v;
    }
    if (ln == 63) warp_part[wv] = sc2;
    __syncthreads();
    if (wv == 0 && ln < 16) {
        int v = warp_part[ln];
        for (int off = 1; off < 16; off <<= 1) {
            int u = __shfl_up(v, off, 64);
            if (ln >= off) v += u;
        }
        warp_part[ln] = v;
    }
    __syncthreads();
    const int wave_off = (wv == 0) ? 0 : warp_part[wv - 1];
    const int excl = wave_off + sc2 - lties;

    // ---- write mask, vectorized ----
    float mv[CHUNK];
    int taken = 0;
#pragma unroll
    for (int j = 0; j < CHUNK; ++j) {
        if (key[j] > tkey) {
            mv[j] = 1.0f;
        } else if (key[j] == tkey) {
            mv[j] = (excl + taken < ties_needed) ? 1.0f : 0.0f;
            ++taken;
        } else {
            mv[j] = 0.0f;
        }
    }
    {
        float4* ov = (float4*)(out + beg);
#pragma unroll
        for (int q = 0; q < CHUNK / 4; ++q)
            ov[q] = make_float4(mv[q * 4 + 0], mv[q * 4 + 1],
                                mv[q * 4 + 2], mv[q * 4 + 3]);
    }

    // ---- aux loss ----
    if (tid == 0) {
        double s = 0.0;
        for (int i = 0; i < 16; ++i) s += sum_sh[i];
        s += (double)ties_needed * (double)__uint_as_float(tkey);
        out[n] = (float)(-(s / (double)k) * 0.001);
    }
}

extern "C" void kernel_launch(void* const* d_in, const int* in_sizes, int n_in,
                              void* d_out, int out_size, void* d_ws, size_t ws_size,
                              hipStream_t stream) {
    const float* x = (const float*)d_in[0];
    // d_in[1] = current_mask, all-True by construction -> no-op in the math
    const float* w = (const float*)d_in[2];

    const int d = in_sizes[2];             // 2048
    const int n = in_sizes[0] / d;         // 16384

    float* scores = (float*)d_ws;                          // n floats
    unsigned int* ticket = (unsigned int*)((char*)d_ws + (size_t)n * 4);
    float* out = (float*)d_out;

    int k = (int)((double)n * 0.67);
    if (k < 1) k = 1;

    (void)hipMemsetAsync(ticket, 0, 4, stream);  // d_ws is poisoned 0xAA each call
    router_fused_kernel<<<n / 16, NSEL_THREADS, 0, stream>>>(
        x, w, scores, ticket, out, n, k);
}

// Round 7
// 206.655 us; speedup vs baseline: 2.1759x; 1.0262x over previous
//
#include <hip/hip_runtime.h>
#include <hip/hip_bf16.h>

// ExpertChoiceRouter: scores = sigmoid(x @ w); top-k (k = int(N*0.67)) mask; aux = -mean(top)*1e-3
// x: [N=16384, D=2048] f32; mask all-True (ignored); w: [1, D] f32
// d_out: N mask floats (0.0/1.0) + 1 aux float.
//
// R6 decision: two-kernel structure (R3, 206.1 us measured) beats fusion.
// Fusion experiments: per-thread __threadfence() = 312 us (L2 wb/inv per
// wave serializes TCC); fence-light ticket design = 212 us (extra memset
// dispatch + ticket protocol + agent-scope stores). Strict producer->consumer
// dependency gains nothing from fusion; the command processor pipelines two
// launches just as well.

#define D_MODEL 2048
#define NSEL_THREADS 1024
#define CHUNK 16            // n / NSEL_THREADS

// ---------------- Kernel 1: per-token dot + sigmoid -------------------------
// wave-per-token; float4 loads; double accumulation for order-stat robustness.
// HBM-bound: 134 MB x-read @ ~6.3 TB/s achievable -> ~21.3 us floor.
__global__ __launch_bounds__(256) void score_kernel(const float* __restrict__ x,
                                                    const float* __restrict__ w,
                                                    float* __restrict__ scores,
                                                    int n_tok) {
    const int wave = threadIdx.x >> 6;
    const int lane = threadIdx.x & 63;
    const int tok  = blockIdx.x * 4 + wave;
    if (tok >= n_tok) return;

    const float4* xr = (const float4*)(x + (size_t)tok * D_MODEL);
    const float4* wr = (const float4*)w;

    double acc = 0.0;
#pragma unroll
    for (int i = 0; i < D_MODEL / 256; ++i) {      // 8 iters, 1KiB/wave each
        float4 xv = xr[i * 64 + lane];
        float4 wv = wr[i * 64 + lane];
        acc += (double)xv.x * (double)wv.x + (double)xv.y * (double)wv.y
             + (double)xv.z * (double)wv.z + (double)xv.w * (double)wv.w;
    }
    for (int off = 32; off > 0; off >>= 1)
        acc += __shfl_down(acc, off, 64);

    if (lane == 0) {
        float logit = (float)acc;
        scores[tok] = 1.0f / (1.0f + expf(-logit));
    }
}

// ---------------- Kernel 2: single-block radix top-k select -----------------
// Keys (positive-float bit patterns, order-preserving) in registers (uint4
// loads). Pass 0's digit (sign+exp byte) is concentrated in ~2 values for
// sigmoid outputs -> leader-ballot aggregation instead of 64-way serialized
// same-address LDS atomics. Passes 1-3: prefix-filtered keys spread over 256
// bins -> plain per-wave-histogram atomics. Bin selection: parallel suffix
// scan over 256 threads.
__global__ __launch_bounds__(NSEL_THREADS) void select_kernel(const float* __restrict__ scores,
                                                              float* __restrict__ out,
                                                              int n, int k) {
    __shared__ unsigned int whist[16 * 257];       // per-wave histograms, padded
    __shared__ int wsum[16];
    __shared__ unsigned int sel_prefix_sh;
    __shared__ int sel_remaining_sh;
    __shared__ int warp_part[16];
    __shared__ double sum_sh[16];

    const int tid = threadIdx.x;
    const int wv  = tid >> 6;
    const int ln  = tid & 63;
    const int beg = tid * CHUNK;

    // ---- load keys once, vectorized (beg is 64B-aligned) ----
    unsigned int key[CHUNK];
    {
        const uint4* sv = (const uint4*)(scores + beg);
#pragma unroll
        for (int q = 0; q < CHUNK / 4; ++q) {
            uint4 v = sv[q];
            key[q * 4 + 0] = v.x; key[q * 4 + 1] = v.y;
            key[q * 4 + 2] = v.z; key[q * 4 + 3] = v.w;
        }
    }

    unsigned int prefix = 0;
    unsigned int pmask  = 0;
    int remaining = k;

#pragma unroll
    for (int pass = 0; pass < 4; ++pass) {
        const int shift = 24 - pass * 8;
        for (int i = tid; i < 16 * 257; i += NSEL_THREADS) whist[i] = 0;
        __syncthreads();

        if (pass == 0) {
            // concentrated digits: leader-ballot aggregated counting
#pragma unroll
            for (int j = 0; j < CHUNK; ++j) {
                unsigned int dig = key[j] >> 24;
                unsigned long long pending = ~0ull;
                while (pending) {
                    int lead = __ffsll((unsigned long long)pending) - 1;
                    unsigned int d0 = __shfl((int)dig, lead, 64);
                    unsigned long long match = __ballot(dig == d0) & pending;
                    if (ln == lead)
                        atomicAdd(&whist[wv * 257 + d0], (unsigned int)__popcll(match));
                    pending &= ~match;
                }
            }
        } else {
#pragma unroll
            for (int j = 0; j < CHUNK; ++j)
                if ((key[j] & pmask) == prefix)
                    atomicAdd(&whist[wv * 257 + ((key[j] >> shift) & 255u)], 1u);
        }
        __syncthreads();

        // threads 0..255: bin totals + parallel suffix scan (bins descending)
        int c = 0;
        if (tid < 256) {
#pragma unroll
            for (int w = 0; w < 16; ++w) c += (int)whist[w * 257 + tid];
        }
        int sc = c;                                 // inclusive suffix within wave
        for (int off = 1; off < 64; off <<= 1) {
            int v = __shfl_down(sc, off, 64);
            if (ln + off < 64) sc += v;
        }
        if (tid < 256 && ln == 0) wsum[wv] = sc;    // wave suffix totals (waves 0..3)
        __syncthreads();
        if (tid < 256) {
            int hi = 0;
            for (int w = wv + 1; w < 4; ++w) hi += wsum[w];
            const int S_excl = hi + (sc - c);       // # keys in strictly-higher bins
            if (S_excl < remaining && remaining <= S_excl + c) {
                sel_prefix_sh    = prefix | ((unsigned int)tid << shift);
                sel_remaining_sh = remaining - S_excl;
            }
        }
        __syncthreads();
        prefix    = sel_prefix_sh;
        remaining = sel_remaining_sh;
        pmask    |= (0xFFu << shift);
        __syncthreads();
    }
    const unsigned int tkey = prefix;     // k-th largest key
    const int ties_needed   = remaining;  // # of ==tkey to take, in index order

    // ---- sum of strictly-greater scores (from registers) ----
    double lsum = 0.0;
#pragma unroll
    for (int j = 0; j < CHUNK; ++j)
        if (key[j] > tkey) lsum += (double)__uint_as_float(key[j]);
    for (int off = 32; off > 0; off >>= 1)
        lsum += __shfl_down(lsum, off, 64);
    if (ln == 0) sum_sh[wv] = lsum;

    // ---- tie ranking: exclusive prefix over per-thread tie counts ----
    int lties = 0;
#pragma unroll
    for (int j = 0; j < CHUNK; ++j)
        if (key[j] == tkey) ++lties;

    int sc2 = lties;                      // inclusive wave scan
    for (int off = 1; off < 64; off <<= 1) {
        int v = __shfl_up(sc2, off, 64);
        if (ln >= off) sc2 += v;
    }
    if (ln == 63) warp_part[wv] = sc2;
    __syncthreads();
    if (wv == 0 && ln < 16) {
        int v = warp_part[ln];
        for (int off = 1; off < 16; off <<= 1) {
            int u = __shfl_up(v, off, 64);
            if (ln >= off) v += u;
        }
        warp_part[ln] = v;                // inclusive wave totals
    }
    __syncthreads();
    const int wave_off = (wv == 0) ? 0 : warp_part[wv - 1];
    const int excl = wave_off + sc2 - lties;

    // ---- write mask, vectorized ----
    float mv[CHUNK];
    int taken = 0;
#pragma unroll
    for (int j = 0; j < CHUNK; ++j) {
        if (key[j] > tkey) {
            mv[j] = 1.0f;
        } else if (key[j] == tkey) {
            mv[j] = (excl + taken < ties_needed) ? 1.0f : 0.0f;
            ++taken;
        } else {
            mv[j] = 0.0f;
        }
    }
    {
        float4* ov = (float4*)(out + beg);
#pragma unroll
        for (int q = 0; q < CHUNK / 4; ++q)
            ov[q] = make_float4(mv[q * 4 + 0], mv[q * 4 + 1],
                                mv[q * 4 + 2], mv[q * 4 + 3]);
    }

    // ---- aux loss ----
    if (tid == 0) {
        double s = 0.0;
        for (int i = 0; i < 16; ++i) s += sum_sh[i];
        s += (double)ties_needed * (double)__uint_as_float(tkey);
        out[n] = (float)(-(s / (double)k) * 0.001);
    }
}

extern "C" void kernel_launch(void* const* d_in, const int* in_sizes, int n_in,
                              void* d_out, int out_size, void* d_ws, size_t ws_size,
                              hipStream_t stream) {
    const float* x = (const float*)d_in[0];
    // d_in[1] = current_mask, all-True by construction -> no-op in the math
    const float* w = (const float*)d_in[2];

    const int d = in_sizes[2];             // 2048
    const int n = in_sizes[0] / d;         // 16384

    float* scores = (float*)d_ws;          // n floats of scratch
    float* out    = (float*)d_out;         // n mask floats + 1 aux

    int k = (int)((double)n * 0.67);
    if (k < 1) k = 1;

    score_kernel<<<(n + 3) / 4, 256, 0, stream>>>(x, w, scores, n);
    select_kernel<<<1, NSEL_THREADS, 0, stream>>>(scores, out, n, k);
}